// Round 1
// baseline (163.999 us; speedup 1.0000x reference)
//
#include <hip/hip_runtime.h>

#define GRID_RES 128
#define N_RAYS 65536
#define N_STEPS 128
#define STEP_SIZE 0.001f

__device__ __forceinline__ float sigmoidf_fast(float x) {
    return 1.0f / (1.0f + __expf(-x));
}

__global__ __launch_bounds__(256) void vr_kernel(
    const float* __restrict__ data,
    const float* __restrict__ origins,
    const float* __restrict__ dirs,
    const float* __restrict__ viewdirs,
    float* __restrict__ out)
{
    int ray = blockIdx.x * blockDim.x + threadIdx.x;
    if (ray >= N_RAYS) return;

    float ox = origins[3*ray+0], oy = origins[3*ray+1], oz = origins[3*ray+2];
    float dx = dirs[3*ray+0],    dy = dirs[3*ray+1],    dz = dirs[3*ray+2];
    float vx = viewdirs[3*ray+0], vy = viewdirs[3*ray+1], vz = viewdirs[3*ray+2];

    // normalize dirs: match numpy rounding (no fma contraction, sqrt+divide)
    {
        float s = __fadd_rn(__fadd_rn(__fmul_rn(dx,dx), __fmul_rn(dy,dy)), __fmul_rn(dz,dz));
        float n = sqrtf(s);
        dx = __fdiv_rn(dx, n); dy = __fdiv_rn(dy, n); dz = __fdiv_rn(dz, n);
    }
    {
        float s = __fadd_rn(__fadd_rn(__fmul_rn(vx,vx), __fmul_rn(vy,vy)), __fmul_rn(vz,vz));
        float n = sqrtf(s);
        vx = __fdiv_rn(vx, n); vy = __fdiv_rn(vy, n); vz = __fdiv_rn(vz, n);
    }

    float invx = __fdiv_rn(1.0f, __fadd_rn(dx, 1e-9f));
    float invy = __fdiv_rn(1.0f, __fadd_rn(dy, 1e-9f));
    float invz = __fdiv_rn(1.0f, __fadd_rn(dz, 1e-9f));

    // dda_unit
    float t1x = __fmul_rn(-ox, invx), t1y = __fmul_rn(-oy, invy), t1z = __fmul_rn(-oz, invz);
    float t2x = __fadd_rn(t1x, invx), t2y = __fadd_rn(t1y, invy), t2z = __fadd_rn(t1z, invz);
    float tmin = fmaxf(fmaxf(fminf(t1x,t2x), fminf(t1y,t2y)), fminf(t1z,t2z));
    tmin = fmaxf(tmin, 0.0f);
    float tmax = fminf(fminf(fmaxf(t1x,t2x), fmaxf(t1y,t2y)), fmaxf(t1z,t2z));
    tmax = fminf(tmax, 1e9f);
    float dt = __fmul_rn(fmaxf(__fsub_rn(tmax, tmin), 0.0f), (1.0f/(float)N_STEPS)); // /128 exact
    float delta_t = __fadd_rn(dt, STEP_SIZE);

    // SH basis (order matches reference)
    const float sh0 = 0.28209479177387814f;
    float sh1 = -0.4886025119029199f * vy;
    float sh2 =  0.4886025119029199f * vz;
    float sh3 = -0.4886025119029199f * vx;
    float sh4 =  1.0925484305920792f * vx * vy;
    float sh5 = -1.0925484305920792f * vy * vz;
    float sh6 =  0.31539156525252005f * (2.0f*vz*vz - vx*vx - vy*vy);
    float sh7 = -1.0925484305920792f * vx * vz;
    float sh8 =  0.5462742152960396f * (vx*vx - vy*vy);

    float light = 1.0f;
    float o_r = 0.0f, o_g = 0.0f, o_b = 0.0f;

    #pragma unroll 4
    for (int i = 0; i < N_STEPS; ++i) {
        // t = tmin + (i+0.5)*dt  (mul then add, rounded like numpy)
        float t = __fadd_rn(tmin, __fmul_rn((float)i + 0.5f, dt));
        // pos = origin + t*dir (no fma contraction: truncation boundary safety)
        float px = __fadd_rn(ox, __fmul_rn(t, dx));
        float py = __fadd_rn(oy, __fmul_rn(t, dy));
        float pz = __fadd_rn(oz, __fmul_rn(t, dz));
        // idx = clip(trunc(pos*128), 0, 127); *128 is exact
        int ix = (int)(px * (float)GRID_RES);
        int iy = (int)(py * (float)GRID_RES);
        int iz = (int)(pz * (float)GRID_RES);
        ix = min(max(ix, 0), GRID_RES-1);
        iy = min(max(iy, 0), GRID_RES-1);
        iz = min(max(iz, 0), GRID_RES-1);

        unsigned lin = (unsigned)(((ix << 7) | iy) << 7 | iz);
        const float4* vp = (const float4*)(data + 28u * lin);  // 16B-aligned (28%4==0)
        float4 c0 = vp[0];
        float4 c1 = vp[1];
        float4 c2 = vp[2];
        float4 c3 = vp[3];
        float4 c4 = vp[4];
        float4 c5 = vp[5];
        float4 c6 = vp[6];

        float sigma = fmaxf(c6.w, 0.0f);
        float att = __expf(-delta_t * sigma);
        float w = light * (1.0f - att);

        float r = sh0*c0.x + sh1*c0.y + sh2*c0.z + sh3*c0.w
                + sh4*c1.x + sh5*c1.y + sh6*c1.z + sh7*c1.w + sh8*c2.x;
        float g = sh0*c2.y + sh1*c2.z + sh2*c2.w + sh3*c3.x
                + sh4*c3.y + sh5*c3.z + sh6*c3.w + sh7*c4.x + sh8*c4.y;
        float b = sh0*c4.z + sh1*c4.w + sh2*c5.x + sh3*c5.y
                + sh4*c5.z + sh5*c5.w + sh6*c6.x + sh7*c6.y + sh8*c6.z;

        o_r = fmaf(w, sigmoidf_fast(r), o_r);
        o_g = fmaf(w, sigmoidf_fast(g), o_g);
        o_b = fmaf(w, sigmoidf_fast(b), o_b);
        light *= att;
    }

    out[3*ray+0] = o_r + light;
    out[3*ray+1] = o_g + light;
    out[3*ray+2] = o_b + light;
}

extern "C" void kernel_launch(void* const* d_in, const int* in_sizes, int n_in,
                              void* d_out, int out_size, void* d_ws, size_t ws_size,
                              hipStream_t stream) {
    const float* data     = (const float*)d_in[0];
    const float* origins  = (const float*)d_in[1];
    const float* dirs     = (const float*)d_in[2];
    const float* viewdirs = (const float*)d_in[3];
    float* out = (float*)d_out;

    dim3 block(256);
    dim3 grid(N_RAYS / 256);
    vr_kernel<<<grid, block, 0, stream>>>(data, origins, dirs, viewdirs, out);
}